// Round 14
// baseline (95.137 us; speedup 1.0000x reference)
//
#include <hip/hip_runtime.h>
#include <math.h>
#include <stdint.h>

#define BATCH 4
#define CH    256
#define HH    80
#define WW    80
#define HW    (HH*WW)        // 6400
#define NPIX  (BATCH*HW)     // 25600
#define KK    9
#define CO    18             // 2*K*K offset channels
#define NCHUNK 72            // 9 taps * 8 groups of 32 channels
#define NIV   36             // K=64 intervals
#define PXB   128            // pixels per k_main block
#define NBLK  (NPIX/PXB)     // 200 blocks (<= 256 CUs: single balanced round)
#define AST   72             // A LDS row stride in halves (144 B)

typedef _Float16 half8 __attribute__((ext_vector_type(8)));
typedef float    f32x4 __attribute__((ext_vector_type(4)));

// ---------------- x NCHW f32 -> xt NHWC f16 ----------------
__global__ __launch_bounds__(256) void k_transpose_x(const float* __restrict__ x,
                                                     _Float16* __restrict__ xt) {
    __shared__ float tile[32][33];
    int b  = blockIdx.z;
    int c0 = blockIdx.y * 32;
    int p0 = blockIdx.x * 32;
    int tx = threadIdx.x;   // 0..31
    int ty = threadIdx.y;   // 0..7
    const float* xb = x + (size_t)b * CH * HW;
    #pragma unroll
    for (int i = 0; i < 32; i += 8)
        tile[ty + i][tx] = xb[(size_t)(c0 + ty + i) * HW + p0 + tx];
    __syncthreads();
    _Float16* xtb = xt + (size_t)b * HW * CH;
    #pragma unroll
    for (int i = 0; i < 32; i += 8)
        xtb[(size_t)(p0 + ty + i) * CH + c0 + tx] = (_Float16)tile[tx][ty + i];
}

// -------- combined weight pack --------
// dcn_w -> wpk4 [NIV][8 og][2 ks][2 nn][64 lane][8 e] f16 ; offset_w -> wopf [72 q][2 nf][64][8]
__global__ __launch_bounds__(256) void k_pack_all(const float* __restrict__ w,
                                                  const float* __restrict__ ow,
                                                  _Float16* __restrict__ wp,
                                                  _Float16* __restrict__ wpo) {
    int idx = blockIdx.x * 256 + threadIdx.x;
    if (idx < NIV * 16384) {
        int e    = idx & 7;
        int lane = (idx >> 3) & 63;
        int nn   = (idx >> 9) & 1;
        int ks   = (idx >> 10) & 1;
        int og   = (idx >> 11) & 7;
        int iv   = idx >> 14;
        int oc = og * 32 + nn * 16 + (lane & 15);
        int kl = ks * 32 + (lane >> 4) * 8 + e;
        int kg = iv * 64 + kl;
        int q  = kg >> 5;
        int tap = q >> 3;
        int c   = (q & 7) * 32 + (kg & 31);
        wp[idx] = (_Float16)w[((size_t)oc * CH + c) * KK + tap];
        return;
    }
    int idx2 = idx - NIV * 16384;
    if (idx2 >= NCHUNK * 1024) return;
    int e    = idx2 & 7;
    int lane = (idx2 >> 3) & 63;
    int nf   = (idx2 >> 9) & 1;
    int q    = idx2 >> 10;
    int oc  = nf * 16 + (lane & 15);
    int kic = (lane >> 4) * 8 + e;
    int tap = q >> 3;
    int c   = (q & 7) * 32 + kic;
    float v = (oc < CO) ? ow[((size_t)oc * CH + c) * KK + tap] : 0.f;
    wpo[idx2] = (_Float16)v;
}

// ---- phase-1 software-pipeline macros (8-deep, named regs: rule-#20 safe) ----
#define P1L(S, Q)                                                                   \
  { int q_ = (Q);                                                                   \
    if (q_ < NCHUNK) {                                                              \
      int tap_ = q_ >> 3, cg_ = q_ & 7;                                             \
      int ki_ = tap_ / 3, kj_ = tap_ - ki_ * 3;                                     \
      int yy_ = h + ki_ - 1, xx_ = w + kj_ - 1;                                     \
      bool ok_ = (yy_ >= 0) && (yy_ < HH) && (xx_ >= 0) && (xx_ < WW);              \
      pa##S = (half8){0, 0, 0, 0, 0, 0, 0, 0};                                      \
      if (ok_) pa##S = *(const half8*)(xtb + (size_t)(yy_ * WW + xx_) * CH + cg_ * 32 + kg8); \
      const _Float16* wq_ = wopf + (size_t)q_ * 1024 + lane * 8;                    \
      pb##S = *(const half8*)(wq_);                                                 \
      pc##S = *(const half8*)(wq_ + 512);                                           \
    } }
#define P1M(S)                                                                      \
  o0 = __builtin_amdgcn_mfma_f32_16x16x32_f16(pa##S, pb##S, o0, 0, 0, 0);           \
  o1 = __builtin_amdgcn_mfma_f32_16x16x32_f16(pa##S, pc##S, o1, 0, 0, 0);

// ---- interval body: B reg-dbuf + A LDS-dbuf, one barrier ----
// wave = 128 px x 32 oc (og), 32 MFMA/interval; gather: 4 thr/px, 2 slots/thr.
#define BODY(IV, BCUR, BNXT, ABR, ABW)                                              \
  {                                                                                 \
    __syncthreads();                                                                \
    const int iv_ = (IV);                                                           \
    half8 pre[2][4]; float cwa[2][4];                                               \
    if (iv_ < NIV - 1) {                                                            \
      const _Float16* wb = wpk4 + (size_t)(iv_ + 1) * 16384 + og * 2048 + lane * 8; \
      BNXT[0] = *(const half8*)(wb);                                                \
      BNXT[1] = *(const half8*)(wb + 512);                                          \
      BNXT[2] = *(const half8*)(wb + 1024);                                         \
      BNXT[3] = *(const half8*)(wb + 1536);                                         \
      _Pragma("unroll")                                                             \
      for (int s = 0; s < 2; ++s) {                                                 \
        int qd = sl + 4 * s;                                                        \
        int sub_ = qd >> 2, ko_ = (qd & 3) * 8;                                     \
        int chunk = 2 * (iv_ + 1) + sub_;                                           \
        int tap_ = chunk >> 3, cg_ = chunk & 7;                                     \
        int4 ncb = cbl[gpx * KK + tap_];                                            \
        float4 ncw = cwl[gpx * KK + tap_];                                          \
        pre[s][0] = *(const half8*)(xtb + (size_t)ncb.x + cg_ * 32 + ko_);          \
        pre[s][1] = *(const half8*)(xtb + (size_t)ncb.y + cg_ * 32 + ko_);          \
        pre[s][2] = *(const half8*)(xtb + (size_t)ncb.z + cg_ * 32 + ko_);          \
        pre[s][3] = *(const half8*)(xtb + (size_t)ncb.w + cg_ * 32 + ko_);          \
        cwa[s][0] = ncw.x; cwa[s][1] = ncw.y; cwa[s][2] = ncw.z; cwa[s][3] = ncw.w; \
      }                                                                             \
    }                                                                               \
    __builtin_amdgcn_s_setprio(1);                                                  \
    _Pragma("unroll")                                                               \
    for (int mm = 0; mm < 8; ++mm) {                                                \
      half8 a0 = *(const half8*)&ABR[(mm * 16 + lm) * AST + kg8];                   \
      half8 a1 = *(const half8*)&ABR[(mm * 16 + lm) * AST + 32 + kg8];              \
      acc[mm][0] = __builtin_amdgcn_mfma_f32_16x16x32_f16(a0, BCUR[0], acc[mm][0], 0, 0, 0); \
      acc[mm][1] = __builtin_amdgcn_mfma_f32_16x16x32_f16(a0, BCUR[1], acc[mm][1], 0, 0, 0); \
      acc[mm][0] = __builtin_amdgcn_mfma_f32_16x16x32_f16(a1, BCUR[2], acc[mm][0], 0, 0, 0); \
      acc[mm][1] = __builtin_amdgcn_mfma_f32_16x16x32_f16(a1, BCUR[3], acc[mm][1], 0, 0, 0); \
    }                                                                               \
    __builtin_amdgcn_s_setprio(0);                                                  \
    if (iv_ < NIV - 1) {                                                            \
      _Pragma("unroll")                                                             \
      for (int s = 0; s < 2; ++s) {                                                 \
        int qd = sl + 4 * s;                                                        \
        half8 v = pre[s][0] * (_Float16)cwa[s][0];                                  \
        v += pre[s][1] * (_Float16)cwa[s][1];                                       \
        v += pre[s][2] * (_Float16)cwa[s][2];                                       \
        v += pre[s][3] * (_Float16)cwa[s][3];                                       \
        *(half8*)&ABW[gpx * AST + qd * 8] = v;                                      \
      }                                                                             \
    }                                                                               \
  }

// ---------------- fully-fused: offset-conv + corners + gather/GEMM + epilogue ----------------
// 200 blocks x 512 thr (8 waves). Phase 1: offset conv, wave og = 16-px frag, full K,
// 8-deep pipelined. Main: wave og = oc group [32*og, 32*og+32), 128 px, B reg-dbuf.
__global__ __launch_bounds__(512, 2) void k_main(const float* __restrict__ x,
                                                 const _Float16* __restrict__ xt,
                                                 const _Float16* __restrict__ wpk4,
                                                 const _Float16* __restrict__ wopf,
                                                 const float* __restrict__ obias,
                                                 const float* __restrict__ gamma,
                                                 const float* __restrict__ beta,
                                                 const float* __restrict__ mean,
                                                 const float* __restrict__ var,
                                                 float* __restrict__ out) {
    __shared__ __align__(16) char pool[73728];
    _Float16* Ab0 = (_Float16*)pool;              // [128*AST] f16  18432 B (buf 0)
    _Float16* Ab1 = (_Float16*)(pool + 18432);    // buf 1          18432 B
    int4*     cbl = (int4*)(pool + 36864);        // [128][9]       18432 B
    float4*   cwl = (float4*)(pool + 55296);      // [128][9]       18432 B
    float*    offl = (float*)pool;                // [128][18] f32 9216 B — aliases Ab0 (dead after phase 2)

    int t = threadIdx.x, lane = t & 63, og = t >> 6;
    int lm = lane & 15, kg8 = (lane >> 4) * 8;
    // bijective XCD swizzle (200 % 8 == 0)
    int tile = ((int)blockIdx.x & 7) * (NBLK / 8) + ((int)blockIdx.x >> 3);
    int pixbase = tile * PXB;
    int bb = pixbase / HW, hw0 = pixbase % HW;
    const _Float16* xtb = xt + (size_t)bb * HW * CH;

    // ---- phase 1: offset conv via MFMA (wave og -> px [og*16, og*16+16), full K) ----
    {
        int apx = hw0 + og * 16 + lm;
        int h = apx / WW, w = apx % WW;
        f32x4 o0 = (f32x4)0.f, o1 = (f32x4)0.f;
        half8 pa0, pa1, pa2, pa3, pa4, pa5, pa6, pa7;
        half8 pb0, pb1, pb2, pb3, pb4, pb5, pb6, pb7;
        half8 pc0, pc1, pc2, pc3, pc4, pc5, pc6, pc7;
        P1L(0, 0) P1L(1, 1) P1L(2, 2) P1L(3, 3)
        P1L(4, 4) P1L(5, 5) P1L(6, 6) P1L(7, 7)
        for (int q = 0; q < NCHUNK; q += 8) {
            P1M(0) P1L(0, q + 8)
            P1M(1) P1L(1, q + 9)
            P1M(2) P1L(2, q + 10)
            P1M(3) P1L(3, q + 11)
            P1M(4) P1L(4, q + 12)
            P1M(5) P1L(5, q + 13)
            P1M(6) P1L(6, q + 14)
            P1M(7) P1L(7, q + 15)
        }
        int prow = og * 16 + (lane >> 4) * 4;
        #pragma unroll
        for (int r = 0; r < 4; ++r) offl[(prow + r) * CO + lm] = o0[r];
        if (lm < CO - 16) {
            #pragma unroll
            for (int r = 0; r < 4; ++r) offl[(prow + r) * CO + 16 + lm] = o1[r];
        }
    }
    __syncthreads();

    // ---- phase 2: bilinear corners/weights for 128 px x 9 taps -> LDS ----
    for (int task = t; task < PXB * KK; task += 512) {
        int p = task / KK, tap = task - (task / KK) * KK;
        float dy = offl[p * CO + 2 * tap]     + obias[2 * tap];
        float dx = offl[p * CO + 2 * tap + 1] + obias[2 * tap + 1];
        int hw = hw0 + p, hc = hw / WW, wc = hw % WW;
        int ki = tap / 3, kj = tap - ki * 3;
        float py = dy + (float)(hc - 1 + ki);
        float px = dx + (float)(wc - 1 + kj);
        float y0f = floorf(py), x0f = floorf(px);
        float wy = py - y0f, wx = px - x0f;
        int y0 = (int)y0f, x0 = (int)x0f;
        int cb[4]; float cw[4];
        #pragma unroll
        for (int cy = 0; cy < 2; ++cy)
            #pragma unroll
            for (int cx = 0; cx < 2; ++cx) {
                int yy = y0 + cy, xx = x0 + cx;
                bool okc = (yy >= 0) && (yy < HH) && (xx >= 0) && (xx < WW);
                int yc = min(max(yy, 0), HH - 1);
                int xc = min(max(xx, 0), WW - 1);
                float wgt = (cy ? wy : 1.f - wy) * (cx ? wx : 1.f - wx);
                cb[cy * 2 + cx] = (yc * WW + xc) * CH;
                cw[cy * 2 + cx] = okc ? wgt : 0.f;
            }
        cbl[task] = make_int4(cb[0], cb[1], cb[2], cb[3]);
        cwl[task] = make_float4(cw[0], cw[1], cw[2], cw[3]);
    }
    __syncthreads();   // offl dead; Ab0 region free to overwrite

    int gpx = t >> 2, sl = t & 3;          // gather: pixel gpx, slots {sl, sl+4}

    // prologue: B(0) -> regs; gather interval 0 (chunks 0,1) -> Ab0
    half8 bfA[4], bfB[4];
    {
        const _Float16* wb = wpk4 + og * 2048 + lane * 8;
        bfA[0] = *(const half8*)(wb);
        bfA[1] = *(const half8*)(wb + 512);
        bfA[2] = *(const half8*)(wb + 1024);
        bfA[3] = *(const half8*)(wb + 1536);
    }
    {
        int4 cb = cbl[gpx * KK];
        float4 cw = cwl[gpx * KK];
        #pragma unroll
        for (int s = 0; s < 2; ++s) {
            int qd = sl + 4 * s;
            int cg = qd >> 2, ko = (qd & 3) * 8;   // chunks 0,1: tap 0, cg = sub
            half8 v = *(const half8*)(xtb + (size_t)cb.x + cg * 32 + ko) * (_Float16)cw.x;
            v += *(const half8*)(xtb + (size_t)cb.y + cg * 32 + ko) * (_Float16)cw.y;
            v += *(const half8*)(xtb + (size_t)cb.z + cg * 32 + ko) * (_Float16)cw.z;
            v += *(const half8*)(xtb + (size_t)cb.w + cg * 32 + ko) * (_Float16)cw.w;
            *(half8*)&Ab0[gpx * AST + qd * 8] = v;
        }
    }

    f32x4 acc[8][2];
    #pragma unroll
    for (int mm = 0; mm < 8; ++mm) {
        acc[mm][0] = (f32x4)0.f;
        acc[mm][1] = (f32x4)0.f;
    }

    for (int ii = 0; ii < NIV; ii += 2) {
        BODY(ii,     bfA, bfB, Ab0, Ab1)
        BODY(ii + 1, bfB, bfA, Ab1, Ab0)
    }

    // --- epilogue: BN + SiLU + residual ---
    const float* xb2  = x   + (size_t)bb * CH * HW;
    float*       outb = out + (size_t)bb * CH * HW;
    #pragma unroll
    for (int nn = 0; nn < 2; ++nn) {
        int oc = og * 32 + nn * 16 + lm;
        float sc = gamma[oc] * rsqrtf(var[oc] + 1e-5f);
        float mn = mean[oc], bt = beta[oc];
        const float* xr   = xb2  + (size_t)oc * HW + hw0;
        float*       orow = outb + (size_t)oc * HW + hw0;
        #pragma unroll
        for (int mm = 0; mm < 8; ++mm) {
            int pb2 = mm * 16 + (lane >> 4) * 4;
            #pragma unroll
            for (int r = 0; r < 4; ++r) {
                float yv = (acc[mm][nn][r] - mn) * sc + bt;
                float s = yv * __builtin_amdgcn_rcpf(1.f + __expf(-yv));
                orow[pb2 + r] = xr[pb2 + r] + s;
            }
        }
    }
}

extern "C" void kernel_launch(void* const* d_in, const int* in_sizes, int n_in,
                              void* d_out, int out_size, void* d_ws, size_t ws_size,
                              hipStream_t stream) {
    const float* x        = (const float*)d_in[0];
    const float* offset_w = (const float*)d_in[1];
    const float* offset_b = (const float*)d_in[2];
    const float* dcn_w    = (const float*)d_in[3];
    const float* gamma    = (const float*)d_in[4];
    const float* beta     = (const float*)d_in[5];
    const float* mean     = (const float*)d_in[6];
    const float* var      = (const float*)d_in[7];
    float* out = (float*)d_out;

    _Float16* xt   = (_Float16*)d_ws;                    // 13,107,200 B
    _Float16* wpk4 = xt + (size_t)NPIX * CH;             //  1,179,648 B
    _Float16* wopf = wpk4 + (size_t)NIV * 16384;         //    147,456 B

    k_transpose_x<<<dim3(HW / 32, CH / 32, BATCH), dim3(32, 8), 0, stream>>>(x, xt);
    k_pack_all<<<(NIV * 16384 + NCHUNK * 1024 + 255) / 256, 256, 0, stream>>>(dcn_w, offset_w, wpk4, wopf);
    k_main<<<NBLK, 512, 0, stream>>>(x, xt, wpk4, wopf, offset_b,
                                     gamma, beta, mean, var, out);
}

// Round 16
// 88.837 us; speedup vs baseline: 1.0709x; 1.0709x over previous
//
#include <hip/hip_runtime.h>
#include <math.h>
#include <stdint.h>

#define BATCH 4
#define CH    256
#define HH    80
#define WW    80
#define HW    (HH*WW)        // 6400
#define NPIX  (BATCH*HW)     // 25600
#define KK    9
#define CO    18             // 2*K*K offset channels
#define NCHUNK 72            // 9 taps * 8 groups of 32 channels
#define NIV   36             // K=64 intervals
#define PXB   64             // pixels per k_main block
#define NBLK  (NPIX/PXB)     // 400 blocks
#define AST   72             // A LDS row stride in halves (144 B)

typedef _Float16 half8 __attribute__((ext_vector_type(8)));
typedef float    f32x4 __attribute__((ext_vector_type(4)));

// ---------------- x NCHW f32 -> xt NHWC f16 ----------------
__global__ __launch_bounds__(256) void k_transpose_x(const float* __restrict__ x,
                                                     _Float16* __restrict__ xt) {
    __shared__ float tile[32][33];
    int b  = blockIdx.z;
    int c0 = blockIdx.y * 32;
    int p0 = blockIdx.x * 32;
    int tx = threadIdx.x;   // 0..31
    int ty = threadIdx.y;   // 0..7
    const float* xb = x + (size_t)b * CH * HW;
    #pragma unroll
    for (int i = 0; i < 32; i += 8)
        tile[ty + i][tx] = xb[(size_t)(c0 + ty + i) * HW + p0 + tx];
    __syncthreads();
    _Float16* xtb = xt + (size_t)b * HW * CH;
    #pragma unroll
    for (int i = 0; i < 32; i += 8)
        xtb[(size_t)(p0 + ty + i) * CH + c0 + tx] = (_Float16)tile[tx][ty + i];
}

// -------- combined weight pack --------
// dcn_w -> wpk4 [NIV][8 og][2 ks][2 nn][64 lane][8 e] f16 ; offset_w -> wopf [72 q][2 nf][64][8]
__global__ __launch_bounds__(256) void k_pack_all(const float* __restrict__ w,
                                                  const float* __restrict__ ow,
                                                  _Float16* __restrict__ wp,
                                                  _Float16* __restrict__ wpo) {
    int idx = blockIdx.x * 256 + threadIdx.x;
    if (idx < NIV * 16384) {
        int e    = idx & 7;
        int lane = (idx >> 3) & 63;
        int nn   = (idx >> 9) & 1;
        int ks   = (idx >> 10) & 1;
        int og   = (idx >> 11) & 7;
        int iv   = idx >> 14;
        int oc = og * 32 + nn * 16 + (lane & 15);
        int kl = ks * 32 + (lane >> 4) * 8 + e;
        int kg = iv * 64 + kl;
        int q  = kg >> 5;
        int tap = q >> 3;
        int c   = (q & 7) * 32 + (kg & 31);
        wp[idx] = (_Float16)w[((size_t)oc * CH + c) * KK + tap];
        return;
    }
    int idx2 = idx - NIV * 16384;
    if (idx2 >= NCHUNK * 1024) return;
    int e    = idx2 & 7;
    int lane = (idx2 >> 3) & 63;
    int nf   = (idx2 >> 9) & 1;
    int q    = idx2 >> 10;
    int oc  = nf * 16 + (lane & 15);
    int kic = (lane >> 4) * 8 + e;
    int tap = q >> 3;
    int c   = (q & 7) * 32 + kic;
    float v = (oc < CO) ? ow[((size_t)oc * CH + c) * KK + tap] : 0.f;
    wpo[idx2] = (_Float16)v;
}

// ---- interval body: B reg-dbuf + A LDS-dbuf, one barrier (R9/R13-proven) ----
#define BODY(IV, IVEND, BCUR, BNXT, RBUF, WBUF)                                    \
  {                                                                                \
    __syncthreads();                                                               \
    const int iv_ = (IV);                                                          \
    half8 pre[4]; float cwa[4];                                                    \
    if (iv_ < (IVEND) - 1) {                                                       \
      const _Float16* wb = wpk4 + (size_t)(iv_ + 1) * 16384 + og * 2048 + lane * 8;\
      BNXT[0] = *(const half8*)(wb);                                               \
      BNXT[1] = *(const half8*)(wb + 512);                                         \
      BNXT[2] = *(const half8*)(wb + 1024);                                        \
      BNXT[3] = *(const half8*)(wb + 1536);                                        \
      int chunk = 2 * (iv_ + 1) + sub;                                             \
      int tap = chunk >> 3, cg = chunk & 7;                                        \
      int4 ncb = cbl[gpx][tap]; float4 ncw = cwl[gpx][tap];                        \
      pre[0] = *(const half8*)(xtb + (size_t)ncb.x + cg * 32 + ko);                \
      pre[1] = *(const half8*)(xtb + (size_t)ncb.y + cg * 32 + ko);                \
      pre[2] = *(const half8*)(xtb + (size_t)ncb.z + cg * 32 + ko);                \
      pre[3] = *(const half8*)(xtb + (size_t)ncb.w + cg * 32 + ko);                \
      cwa[0] = ncw.x; cwa[1] = ncw.y; cwa[2] = ncw.z; cwa[3] = ncw.w;              \
    }                                                                              \
    __builtin_amdgcn_s_setprio(1);                                                 \
    _Pragma("unroll")                                                              \
    for (int mm = 0; mm < 4; ++mm) {                                               \
      half8 a0 = *(const half8*)&Ab[RBUF][(mm * 16 + lm) * AST + kg8];             \
      half8 a1 = *(const half8*)&Ab[RBUF][(mm * 16 + lm) * AST + 32 + kg8];        \
      acc[mm][0] = __builtin_amdgcn_mfma_f32_16x16x32_f16(a0, BCUR[0], acc[mm][0], 0, 0, 0); \
      acc[mm][1] = __builtin_amdgcn_mfma_f32_16x16x32_f16(a0, BCUR[1], acc[mm][1], 0, 0, 0); \
      acc[mm][0] = __builtin_amdgcn_mfma_f32_16x16x32_f16(a1, BCUR[2], acc[mm][0], 0, 0, 0); \
      acc[mm][1] = __builtin_amdgcn_mfma_f32_16x16x32_f16(a1, BCUR[3], acc[mm][1], 0, 0, 0); \
    }                                                                              \
    __builtin_amdgcn_s_setprio(0);                                                 \
    if (iv_ < (IVEND) - 1) {                                                       \
      half8 v = pre[0] * (_Float16)cwa[0];                                         \
      v += pre[1] * (_Float16)cwa[1];                                              \
      v += pre[2] * (_Float16)cwa[2];                                              \
      v += pre[3] * (_Float16)cwa[3];                                              \
      *(half8*)&Ab[WBUF][gpx * AST + cq * 8] = v;                                  \
    }                                                                              \
  }

// ---------------- fully-fused: offset-conv + corners + gather/GEMM + epilogue ----------------
// 512 thr = 8 waves.
// Phase 1: offset conv via MFMA. wave = (pxh=og&1: 32-px half) x (kq=og>>1: 18-chunk K-quarter).
//   Each wave runs TWO independent 16-px fragment streams over an 18-chunk chain
//   (vs R13's single 36-chunk chain) -> 4x the latency cover at the same reg budget.
//   Partials offl[4][64][18] alias the Ab region (dead before Ab's first write; R14-proven).
// Main loop: R9/R13-proven (8 og-waves, B reg-dbuf, A LDS-dbuf, 1 barrier/interval).
__global__ __launch_bounds__(512, 4) void k_main(const float* __restrict__ x,
                                                 const _Float16* __restrict__ xt,
                                                 const _Float16* __restrict__ wpk4,
                                                 const _Float16* __restrict__ wopf,
                                                 const float* __restrict__ obias,
                                                 const float* __restrict__ gamma,
                                                 const float* __restrict__ beta,
                                                 const float* __restrict__ mean,
                                                 const float* __restrict__ var,
                                                 float* __restrict__ out) {
    __shared__ __align__(16) char pool[46080];
    _Float16 (*Ab)[PXB * AST] = (_Float16 (*)[PXB * AST])pool;   // [2][4608] f16 = 18432 B
    int4   (*cbl)[KK] = (int4 (*)[KK])(pool + 18432);            // [64][9] = 9216 B
    float4 (*cwl)[KK] = (float4 (*)[KK])(pool + 27648);          // [64][9] = 9216 B
    float*  offl      = (float*)pool;                            // [4][64][18] f32 = 18432 B, aliases Ab
    // remaining 9216 B (pool+36864..46080) unused; keeps LDS size == R13's 46080.

    int t = threadIdx.x, lane = t & 63, og = t >> 6;
    int lm = lane & 15, kg8 = (lane >> 4) * 8;
    // bijective XCD swizzle (400 % 8 == 0)
    int tile = ((int)blockIdx.x & 7) * (NBLK / 8) + ((int)blockIdx.x >> 3);
    int pixbase = tile * PXB;
    int bb = pixbase / HW, hw0 = pixbase % HW;
    const _Float16* xtb = xt + (size_t)bb * HW * CH;

    // ---- phase 1: offset conv via MFMA, 2 px-frag streams x 18-chunk K-quarter ----
    {
        int pxh = og & 1;                 // pixel half: px [pxh*32, pxh*32+32)
        int kq  = og >> 1;                // K quarter: chunks [kq*18, kq*18+18)
        int apx0 = hw0 + pxh * 32 + lm;   // frag 0 pixel (rows 0-15 of half)
        int apx1 = apx0 + 16;             // frag 1 pixel (rows 16-31 of half)
        int h0 = apx0 / WW, w0 = apx0 % WW;
        int h1 = apx1 / WW, w1 = apx1 % WW;
        f32x4 oa0 = (f32x4)0.f, oa1 = (f32x4)0.f;   // frag0 x (oc 0-15, 16-31)
        f32x4 ob0 = (f32x4)0.f, ob1 = (f32x4)0.f;   // frag1 x (oc 0-15, 16-31)
        #pragma unroll
        for (int qq = 0; qq < 18; ++qq) {
            int q = kq * 18 + qq;
            int tap = q >> 3, cg = q & 7;
            int ki = tap / 3, kj = tap - ki * 3;
            int yy0 = h0 + ki - 1, xx0 = w0 + kj - 1;
            int yy1 = h1 + ki - 1, xx1 = w1 + kj - 1;
            bool ok0 = (yy0 >= 0) && (yy0 < HH) && (xx0 >= 0) && (xx0 < WW);
            bool ok1 = (yy1 >= 0) && (yy1 < HH) && (xx1 >= 0) && (xx1 < WW);
            half8 a0 = {0, 0, 0, 0, 0, 0, 0, 0};
            half8 a1 = {0, 0, 0, 0, 0, 0, 0, 0};
            if (ok0) a0 = *(const half8*)(xtb + (size_t)(yy0 * WW + xx0) * CH + cg * 32 + kg8);
            if (ok1) a1 = *(const half8*)(xtb + (size_t)(yy1 * WW + xx1) * CH + cg * 32 + kg8);
            const _Float16* wq = wopf + (size_t)q * 1024 + lane * 8;
            half8 b0 = *(const half8*)(wq);
            half8 b1 = *(const half8*)(wq + 512);
            oa0 = __builtin_amdgcn_mfma_f32_16x16x32_f16(a0, b0, oa0, 0, 0, 0);
            oa1 = __builtin_amdgcn_mfma_f32_16x16x32_f16(a0, b1, oa1, 0, 0, 0);
            ob0 = __builtin_amdgcn_mfma_f32_16x16x32_f16(a1, b0, ob0, 0, 0, 0);
            ob1 = __builtin_amdgcn_mfma_f32_16x16x32_f16(a1, b1, ob1, 0, 0, 0);
        }
        // D layout: oc = lm, px-row = (lane>>4)*4 + r
        int prow = (lane >> 4) * 4;
        int r0 = (kq * PXB) + pxh * 32 + prow;        // frag0 rows
        int r1 = r0 + 16;                             // frag1 rows
        #pragma unroll
        for (int r = 0; r < 4; ++r) {
            offl[(r0 + r) * CO + lm] = oa0[r];
            offl[(r1 + r) * CO + lm] = ob0[r];
        }
        if (lm < CO - 16) {
            #pragma unroll
            for (int r = 0; r < 4; ++r) {
                offl[(r0 + r) * CO + 16 + lm] = oa1[r];
                offl[(r1 + r) * CO + 16 + lm] = ob1[r];
            }
        }
    }
    __syncthreads();

    // ---- phase 2: bilinear corners/weights for 64 px x 9 taps -> LDS ----
    for (int task = t; task < PXB * KK; task += 512) {
        int p = task / KK, tap = task - (task / KK) * KK;
        float dy = obias[2 * tap], dx = obias[2 * tap + 1];
        #pragma unroll
        for (int ks = 0; ks < 4; ++ks) {
            dy += offl[((ks * PXB) + p) * CO + 2 * tap];
            dx += offl[((ks * PXB) + p) * CO + 2 * tap + 1];
        }
        int hw = hw0 + p, hc = hw / WW, wc = hw % WW;
        int ki = tap / 3, kj = tap - ki * 3;
        float py = dy + (float)(hc - 1 + ki);
        float px = dx + (float)(wc - 1 + kj);
        float y0f = floorf(py), x0f = floorf(px);
        float wy = py - y0f, wx = px - x0f;
        int y0 = (int)y0f, x0 = (int)x0f;
        int cb[4]; float cw[4];
        #pragma unroll
        for (int cy = 0; cy < 2; ++cy)
            #pragma unroll
            for (int cx = 0; cx < 2; ++cx) {
                int yy = y0 + cy, xx = x0 + cx;
                bool okc = (yy >= 0) && (yy < HH) && (xx >= 0) && (xx < WW);
                int yc = min(max(yy, 0), HH - 1);
                int xc = min(max(xx, 0), WW - 1);
                float wgt = (cy ? wy : 1.f - wy) * (cx ? wx : 1.f - wx);
                cb[cy * 2 + cx] = (yc * WW + xc) * CH;
                cw[cy * 2 + cx] = okc ? wgt : 0.f;
            }
        cbl[p][tap] = make_int4(cb[0], cb[1], cb[2], cb[3]);
        cwl[p][tap] = make_float4(cw[0], cw[1], cw[2], cw[3]);
    }
    __syncthreads();   // offl dead beyond this point; Ab region free to overwrite

    int gpx = t >> 3, cq = t & 7;
    int sub = cq >> 2, ko = (cq & 3) * 8;

    // prologue: B(0) -> regs; gather interval 0 (chunks 0,1) -> Ab[0]
    half8 bfA[4], bfB[4];
    {
        const _Float16* wb = wpk4 + og * 2048 + lane * 8;
        bfA[0] = *(const half8*)(wb);
        bfA[1] = *(const half8*)(wb + 512);
        bfA[2] = *(const half8*)(wb + 1024);
        bfA[3] = *(const half8*)(wb + 1536);
    }
    {
        int4 cb = cbl[gpx][0];
        float4 cw = cwl[gpx][0];
        int cg = sub;                       // chunks 0,1: tap 0
        half8 v = *(const half8*)(xtb + (size_t)cb.x + cg * 32 + ko) * (_Float16)cw.x;
        v += *(const half8*)(xtb + (size_t)cb.y + cg * 32 + ko) * (_Float16)cw.y;
        v += *(const half8*)(xtb + (size_t)cb.z + cg * 32 + ko) * (_Float16)cw.z;
        v += *(const half8*)(xtb + (size_t)cb.w + cg * 32 + ko) * (_Float16)cw.w;
        *(half8*)&Ab[0][gpx * AST + cq * 8] = v;
    }

    f32x4 acc[4][2];
    #pragma unroll
    for (int mm = 0; mm < 4; ++mm) {
        acc[mm][0] = (f32x4)0.f;
        acc[mm][1] = (f32x4)0.f;
    }

    for (int ii = 0; ii < NIV; ii += 2) {
        BODY(ii,     NIV, bfA, bfB, 0, 1)
        BODY(ii + 1, NIV, bfB, bfA, 1, 0)
    }

    // --- epilogue: BN + SiLU + residual ---
    const float* xb2  = x   + (size_t)bb * CH * HW;
    float*       outb = out + (size_t)bb * CH * HW;
    #pragma unroll
    for (int nn = 0; nn < 2; ++nn) {
        int oc = og * 32 + nn * 16 + lm;
        float sc = gamma[oc] * rsqrtf(var[oc] + 1e-5f);
        float mn = mean[oc], bt = beta[oc];
        const float* xr   = xb2  + (size_t)oc * HW + hw0;
        float*       orow = outb + (size_t)oc * HW + hw0;
        #pragma unroll
        for (int mm = 0; mm < 4; ++mm) {
            int pb2 = mm * 16 + (lane >> 4) * 4;
            #pragma unroll
            for (int r = 0; r < 4; ++r) {
                float yv = (acc[mm][nn][r] - mn) * sc + bt;
                float s = yv * __builtin_amdgcn_rcpf(1.f + __expf(-yv));
                orow[pb2 + r] = xr[pb2 + r] + s;
            }
        }
    }
}

extern "C" void kernel_launch(void* const* d_in, const int* in_sizes, int n_in,
                              void* d_out, int out_size, void* d_ws, size_t ws_size,
                              hipStream_t stream) {
    const float* x        = (const float*)d_in[0];
    const float* offset_w = (const float*)d_in[1];
    const float* offset_b = (const float*)d_in[2];
    const float* dcn_w    = (const float*)d_in[3];
    const float* gamma    = (const float*)d_in[4];
    const float* beta     = (const float*)d_in[5];
    const float* mean     = (const float*)d_in[6];
    const float* var      = (const float*)d_in[7];
    float* out = (float*)d_out;

    _Float16* xt   = (_Float16*)d_ws;                    // 13,107,200 B
    _Float16* wpk4 = xt + (size_t)NPIX * CH;             //  1,179,648 B
    _Float16* wopf = wpk4 + (size_t)NIV * 16384;         //    147,456 B

    k_transpose_x<<<dim3(HW / 32, CH / 32, BATCH), dim3(32, 8), 0, stream>>>(x, xt);
    k_pack_all<<<(NIV * 16384 + NCHUNK * 1024 + 255) / 256, 256, 0, stream>>>(dcn_w, offset_w, wpk4, wopf);
    k_main<<<NBLK, 512, 0, stream>>>(x, xt, wpk4, wopf, offset_b,
                                     gamma, beta, mean, var, out);
}

// Round 17
// 85.444 us; speedup vs baseline: 1.1134x; 1.0397x over previous
//
#include <hip/hip_runtime.h>
#include <math.h>
#include <stdint.h>

#define BATCH 4
#define CH    256
#define HH    80
#define WW    80
#define HW    (HH*WW)        // 6400
#define NPIX  (BATCH*HW)     // 25600
#define KK    9
#define CO    18             // 2*K*K offset channels
#define NCHUNK 72            // 9 taps * 8 groups of 32 channels
#define NIV   36             // K=64 intervals
#define NSUP  18             // K=128 super-intervals (2 per barrier)
#define PXB   64             // pixels per k_main block
#define NBLK  (NPIX/PXB)     // 400 blocks
#define AST   72             // A LDS row stride in halves (144 B)
#define SUBSZ (PXB*AST)      // 4608 halves per A sub-buffer

typedef _Float16 half8 __attribute__((ext_vector_type(8)));
typedef float    f32x4 __attribute__((ext_vector_type(4)));

// -------- merged prep: x NCHW f32 -> xt NHWC f16  +  weight packs --------
#define TRN_BLOCKS 6400   // (HW/32)*(CH/32)*BATCH
__global__ __launch_bounds__(256) void k_prep(const float* __restrict__ x,
                                              _Float16* __restrict__ xt,
                                              const float* __restrict__ w,
                                              const float* __restrict__ ow,
                                              _Float16* __restrict__ wp,
                                              _Float16* __restrict__ wpo) {
    __shared__ float tile[32][33];
    int bid = blockIdx.x;
    if (bid < TRN_BLOCKS) {
        int b  = bid / 1600;
        int c0 = ((bid / 200) & 7) * 32;
        int p0 = (bid % 200) * 32;
        int tx = threadIdx.x & 31, ty = threadIdx.x >> 5;   // 32 x 8
        const float* xb = x + (size_t)b * CH * HW;
        #pragma unroll
        for (int i = 0; i < 32; i += 8)
            tile[ty + i][tx] = xb[(size_t)(c0 + ty + i) * HW + p0 + tx];
        __syncthreads();
        _Float16* xtb = xt + (size_t)b * HW * CH;
        #pragma unroll
        for (int i = 0; i < 32; i += 8)
            xtb[(size_t)(p0 + ty + i) * CH + c0 + tx] = (_Float16)tile[tx][ty + i];
        return;
    }
    int idx = (bid - TRN_BLOCKS) * 256 + threadIdx.x;
    if (idx < NIV * 16384) {
        int e    = idx & 7;
        int lane = (idx >> 3) & 63;
        int nn   = (idx >> 9) & 1;
        int ks   = (idx >> 10) & 1;
        int og   = (idx >> 11) & 7;
        int iv   = idx >> 14;
        int oc = og * 32 + nn * 16 + (lane & 15);
        int kl = ks * 32 + (lane >> 4) * 8 + e;
        int kg = iv * 64 + kl;
        int q  = kg >> 5;
        int tap = q >> 3;
        int c   = (q & 7) * 32 + (kg & 31);
        wp[idx] = (_Float16)w[((size_t)oc * CH + c) * KK + tap];
        return;
    }
    int idx2 = idx - NIV * 16384;
    if (idx2 >= NCHUNK * 1024) return;
    int e    = idx2 & 7;
    int lane = (idx2 >> 3) & 63;
    int nf   = (idx2 >> 9) & 1;
    int q    = idx2 >> 10;
    int oc  = nf * 16 + (lane & 15);
    int kic = (lane >> 4) * 8 + e;
    int tap = q >> 3;
    int c   = (q & 7) * 32 + kic;
    float v = (oc < CO) ? ow[((size_t)oc * CH + c) * KK + tap] : 0.f;
    wpo[idx2] = (_Float16)v;
}

// ---- main-loop building blocks ----
#define LOADB(DST, IV) { \
    const _Float16* wb_ = wpk4 + (size_t)(IV) * 16384 + og * 2048 + lane * 8; \
    DST[0] = *(const half8*)(wb_);        DST[1] = *(const half8*)(wb_ + 512); \
    DST[2] = *(const half8*)(wb_ + 1024); DST[3] = *(const half8*)(wb_ + 1536); }

#define LOADPRE(PRE, CWA, CHUNK) { \
    int tap_ = (CHUNK) >> 3, cg_ = (CHUNK) & 7; \
    int4 ncb_ = cbl[gpx][tap_]; float4 ncw_ = cwl[gpx][tap_]; \
    PRE[0] = *(const half8*)(xtb + (size_t)ncb_.x + cg_ * 32 + ko); \
    PRE[1] = *(const half8*)(xtb + (size_t)ncb_.y + cg_ * 32 + ko); \
    PRE[2] = *(const half8*)(xtb + (size_t)ncb_.z + cg_ * 32 + ko); \
    PRE[3] = *(const half8*)(xtb + (size_t)ncb_.w + cg_ * 32 + ko); \
    CWA[0] = ncw_.x; CWA[1] = ncw_.y; CWA[2] = ncw_.z; CWA[3] = ncw_.w; }

#define MFMA8(BASE, BF) { \
    __builtin_amdgcn_s_setprio(1); \
    _Pragma("unroll") \
    for (int mm = 0; mm < 4; ++mm) { \
      half8 a0 = *(const half8*)&(BASE)[(mm * 16 + lm) * AST + kg8]; \
      half8 a1 = *(const half8*)&(BASE)[(mm * 16 + lm) * AST + 32 + kg8]; \
      acc[mm][0] = __builtin_amdgcn_mfma_f32_16x16x32_f16(a0, BF[0], acc[mm][0], 0, 0, 0); \
      acc[mm][1] = __builtin_amdgcn_mfma_f32_16x16x32_f16(a0, BF[1], acc[mm][1], 0, 0, 0); \
      acc[mm][0] = __builtin_amdgcn_mfma_f32_16x16x32_f16(a1, BF[2], acc[mm][0], 0, 0, 0); \
      acc[mm][1] = __builtin_amdgcn_mfma_f32_16x16x32_f16(a1, BF[3], acc[mm][1], 0, 0, 0); \
    } \
    __builtin_amdgcn_s_setprio(0); }

#define BLEND(PRE, CWA, DSTBASE) { \
    half8 v_ = PRE[0] * (_Float16)CWA[0]; \
    v_ += PRE[1] * (_Float16)CWA[1]; \
    v_ += PRE[2] * (_Float16)CWA[2]; \
    v_ += PRE[3] * (_Float16)CWA[3]; \
    *(half8*)&(DSTBASE)[gpx * AST + cq * 8] = v_; }

// ---------------- fully-fused: offset-conv + corners + gather/GEMM + epilogue ----------------
// 512 thr = 8 waves. Phase 1: R16-proven (2 px-frag streams x 18-chunk K-quarter per wave).
// Main loop: 18 super-intervals (K=128), ONE barrier each; 4 A sub-buffers buf(super,sub);
// B reg-dbuf invariant: bfA = B(2j) at super start; bfB loaded in-body for B(2j+1).
__global__ __launch_bounds__(512, 4) void k_main(const float* __restrict__ x,
                                                 const _Float16* __restrict__ xt,
                                                 const _Float16* __restrict__ wpk4,
                                                 const _Float16* __restrict__ wopf,
                                                 const float* __restrict__ obias,
                                                 const float* __restrict__ gamma,
                                                 const float* __restrict__ beta,
                                                 const float* __restrict__ mean,
                                                 const float* __restrict__ var,
                                                 float* __restrict__ out) {
    __shared__ __align__(16) char pool[55296];
    _Float16* AbF = (_Float16*)pool;                             // [4][SUBSZ] f16 = 36864 B
    int4   (*cbl)[KK] = (int4 (*)[KK])(pool + 36864);            // [64][9] = 9216 B
    float4 (*cwl)[KK] = (float4 (*)[KK])(pool + 46080);          // [64][9] = 9216 B
    float*  offl      = (float*)pool;                            // [4][64][18] f32 = 18432 B, aliases AbF

    int t = threadIdx.x, lane = t & 63, og = t >> 6;
    int lm = lane & 15, kg8 = (lane >> 4) * 8;
    // bijective XCD swizzle (400 % 8 == 0)
    int tile = ((int)blockIdx.x & 7) * (NBLK / 8) + ((int)blockIdx.x >> 3);
    int pixbase = tile * PXB;
    int bb = pixbase / HW, hw0 = pixbase % HW;
    const _Float16* xtb = xt + (size_t)bb * HW * CH;

    // ---- phase 1: offset conv via MFMA (R16-proven: 2 px-frag streams x K-quarter) ----
    {
        int pxh = og & 1;                 // pixel half: px [pxh*32, pxh*32+32)
        int kq  = og >> 1;                // K quarter: chunks [kq*18, kq*18+18)
        int apx0 = hw0 + pxh * 32 + lm;
        int apx1 = apx0 + 16;
        int h0 = apx0 / WW, w0 = apx0 % WW;
        int h1 = apx1 / WW, w1 = apx1 % WW;
        f32x4 oa0 = (f32x4)0.f, oa1 = (f32x4)0.f;
        f32x4 ob0 = (f32x4)0.f, ob1 = (f32x4)0.f;
        #pragma unroll
        for (int qq = 0; qq < 18; ++qq) {
            int q = kq * 18 + qq;
            int tap = q >> 3, cg = q & 7;
            int ki = tap / 3, kj = tap - ki * 3;
            int yy0 = h0 + ki - 1, xx0 = w0 + kj - 1;
            int yy1 = h1 + ki - 1, xx1 = w1 + kj - 1;
            bool ok0 = (yy0 >= 0) && (yy0 < HH) && (xx0 >= 0) && (xx0 < WW);
            bool ok1 = (yy1 >= 0) && (yy1 < HH) && (xx1 >= 0) && (xx1 < WW);
            half8 a0 = {0, 0, 0, 0, 0, 0, 0, 0};
            half8 a1 = {0, 0, 0, 0, 0, 0, 0, 0};
            if (ok0) a0 = *(const half8*)(xtb + (size_t)(yy0 * WW + xx0) * CH + cg * 32 + kg8);
            if (ok1) a1 = *(const half8*)(xtb + (size_t)(yy1 * WW + xx1) * CH + cg * 32 + kg8);
            const _Float16* wq = wopf + (size_t)q * 1024 + lane * 8;
            half8 b0 = *(const half8*)(wq);
            half8 b1 = *(const half8*)(wq + 512);
            oa0 = __builtin_amdgcn_mfma_f32_16x16x32_f16(a0, b0, oa0, 0, 0, 0);
            oa1 = __builtin_amdgcn_mfma_f32_16x16x32_f16(a0, b1, oa1, 0, 0, 0);
            ob0 = __builtin_amdgcn_mfma_f32_16x16x32_f16(a1, b0, ob0, 0, 0, 0);
            ob1 = __builtin_amdgcn_mfma_f32_16x16x32_f16(a1, b1, ob1, 0, 0, 0);
        }
        int prow = (lane >> 4) * 4;
        int r0 = (kq * PXB) + pxh * 32 + prow;
        int r1 = r0 + 16;
        #pragma unroll
        for (int r = 0; r < 4; ++r) {
            offl[(r0 + r) * CO + lm] = oa0[r];
            offl[(r1 + r) * CO + lm] = ob0[r];
        }
        if (lm < CO - 16) {
            #pragma unroll
            for (int r = 0; r < 4; ++r) {
                offl[(r0 + r) * CO + 16 + lm] = oa1[r];
                offl[(r1 + r) * CO + 16 + lm] = ob1[r];
            }
        }
    }
    __syncthreads();

    // ---- phase 2: bilinear corners/weights for 64 px x 9 taps -> LDS ----
    for (int task = t; task < PXB * KK; task += 512) {
        int p = task / KK, tap = task - (task / KK) * KK;
        float dy = obias[2 * tap], dx = obias[2 * tap + 1];
        #pragma unroll
        for (int ks = 0; ks < 4; ++ks) {
            dy += offl[((ks * PXB) + p) * CO + 2 * tap];
            dx += offl[((ks * PXB) + p) * CO + 2 * tap + 1];
        }
        int hw = hw0 + p, hc = hw / WW, wc = hw % WW;
        int ki = tap / 3, kj = tap - ki * 3;
        float py = dy + (float)(hc - 1 + ki);
        float px = dx + (float)(wc - 1 + kj);
        float y0f = floorf(py), x0f = floorf(px);
        float wy = py - y0f, wx = px - x0f;
        int y0 = (int)y0f, x0 = (int)x0f;
        int cb[4]; float cw[4];
        #pragma unroll
        for (int cy = 0; cy < 2; ++cy)
            #pragma unroll
            for (int cx = 0; cx < 2; ++cx) {
                int yy = y0 + cy, xx = x0 + cx;
                bool okc = (yy >= 0) && (yy < HH) && (xx >= 0) && (xx < WW);
                int yc = min(max(yy, 0), HH - 1);
                int xc = min(max(xx, 0), WW - 1);
                float wgt = (cy ? wy : 1.f - wy) * (cx ? wx : 1.f - wx);
                cb[cy * 2 + cx] = (yc * WW + xc) * CH;
                cw[cy * 2 + cx] = okc ? wgt : 0.f;
            }
        cbl[p][tap] = make_int4(cb[0], cb[1], cb[2], cb[3]);
        cwl[p][tap] = make_float4(cw[0], cw[1], cw[2], cw[3]);
    }
    __syncthreads();   // offl dead beyond this point; AbF free to overwrite

    int gpx = t >> 3, cq = t & 7;
    int sub = cq >> 2, ko = (cq & 3) * 8;

    // prologue: bfA <- B(0); gather intervals 0,1 -> buf(0,0), buf(0,1)
    half8 bfA[4], bfB[4];
    LOADB(bfA, 0)
    {
        int4 cb = cbl[gpx][0];
        float4 cw = cwl[gpx][0];
        int cg = sub;                       // interval 0: chunks 0,1 (tap 0)
        half8 v = *(const half8*)(xtb + (size_t)cb.x + cg * 32 + ko) * (_Float16)cw.x;
        v += *(const half8*)(xtb + (size_t)cb.y + cg * 32 + ko) * (_Float16)cw.y;
        v += *(const half8*)(xtb + (size_t)cb.z + cg * 32 + ko) * (_Float16)cw.z;
        v += *(const half8*)(xtb + (size_t)cb.w + cg * 32 + ko) * (_Float16)cw.w;
        *(half8*)&AbF[gpx * AST + cq * 8] = v;
        int cg2 = 2 + sub;                  // interval 1: chunks 2,3 (tap 0)
        half8 v2 = *(const half8*)(xtb + (size_t)cb.x + cg2 * 32 + ko) * (_Float16)cw.x;
        v2 += *(const half8*)(xtb + (size_t)cb.y + cg2 * 32 + ko) * (_Float16)cw.y;
        v2 += *(const half8*)(xtb + (size_t)cb.z + cg2 * 32 + ko) * (_Float16)cw.z;
        v2 += *(const half8*)(xtb + (size_t)cb.w + cg2 * 32 + ko) * (_Float16)cw.w;
        *(half8*)&AbF[SUBSZ + gpx * AST + cq * 8] = v2;
    }

    f32x4 acc[4][2];
    #pragma unroll
    for (int mm = 0; mm < 4; ++mm) {
        acc[mm][0] = (f32x4)0.f;
        acc[mm][1] = (f32x4)0.f;
    }

    // ---- main loop: 18 super-intervals, ONE barrier each ----
    for (int j = 0; j < NSUP; ++j) {
        int rs = j & 1, ws = rs ^ 1;
        _Float16* bufR0 = AbF + (rs * 2 + 0) * SUBSZ;
        _Float16* bufR1 = AbF + (rs * 2 + 1) * SUBSZ;
        _Float16* bufW0 = AbF + (ws * 2 + 0) * SUBSZ;
        _Float16* bufW1 = AbF + (ws * 2 + 1) * SUBSZ;
        bool gnext = (j < NSUP - 1);
        __syncthreads();
        LOADB(bfB, 2 * j + 1)
        half8 pre0[4]; float cw0[4];
        if (gnext) LOADPRE(pre0, cw0, 4 * j + 4 + sub)
        MFMA8(bufR0, bfA)                     // interval 2j
        if (gnext) BLEND(pre0, cw0, bufW0)
        if (gnext) LOADB(bfA, 2 * j + 2)
        half8 pre1[4]; float cw1[4];
        if (gnext) LOADPRE(pre1, cw1, 4 * j + 6 + sub)
        MFMA8(bufR1, bfB)                     // interval 2j+1
        if (gnext) BLEND(pre1, cw1, bufW1)
    }

    // --- epilogue: BN + SiLU + residual ---
    const float* xb2  = x   + (size_t)bb * CH * HW;
    float*       outb = out + (size_t)bb * CH * HW;
    #pragma unroll
    for (int nn = 0; nn < 2; ++nn) {
        int oc = og * 32 + nn * 16 + lm;
        float sc = gamma[oc] * rsqrtf(var[oc] + 1e-5f);
        float mn = mean[oc], bt = beta[oc];
        const float* xr   = xb2  + (size_t)oc * HW + hw0;
        float*       orow = outb + (size_t)oc * HW + hw0;
        #pragma unroll
        for (int mm = 0; mm < 4; ++mm) {
            int pb2 = mm * 16 + (lane >> 4) * 4;
            #pragma unroll
            for (int r = 0; r < 4; ++r) {
                float yv = (acc[mm][nn][r] - mn) * sc + bt;
                float s = yv * __builtin_amdgcn_rcpf(1.f + __expf(-yv));
                orow[pb2 + r] = xr[pb2 + r] + s;
            }
        }
    }
}

extern "C" void kernel_launch(void* const* d_in, const int* in_sizes, int n_in,
                              void* d_out, int out_size, void* d_ws, size_t ws_size,
                              hipStream_t stream) {
    const float* x        = (const float*)d_in[0];
    const float* offset_w = (const float*)d_in[1];
    const float* offset_b = (const float*)d_in[2];
    const float* dcn_w    = (const float*)d_in[3];
    const float* gamma    = (const float*)d_in[4];
    const float* beta     = (const float*)d_in[5];
    const float* mean     = (const float*)d_in[6];
    const float* var      = (const float*)d_in[7];
    float* out = (float*)d_out;

    _Float16* xt   = (_Float16*)d_ws;                    // 13,107,200 B
    _Float16* wpk4 = xt + (size_t)NPIX * CH;             //  1,179,648 B
    _Float16* wopf = wpk4 + (size_t)NIV * 16384;         //    147,456 B

    int prep_blocks = TRN_BLOCKS + (NIV * 16384 + NCHUNK * 1024 + 255) / 256;
    k_prep<<<prep_blocks, 256, 0, stream>>>(x, xt, dcn_w, offset_w, wpk4, wopf);
    k_main<<<NBLK, 512, 0, stream>>>(x, xt, wpk4, wopf, offset_b,
                                     gamma, beta, mean, var, out);
}

// Round 18
// 85.039 us; speedup vs baseline: 1.1187x; 1.0048x over previous
//
#include <hip/hip_runtime.h>
#include <math.h>
#include <stdint.h>

#define BATCH 4
#define CH    256
#define HH    80
#define WW    80
#define HW    (HH*WW)        // 6400
#define NPIX  (BATCH*HW)     // 25600
#define KK    9
#define CO    18             // 2*K*K offset channels
#define NCHUNK 72            // 9 taps * 8 groups of 32 channels
#define NIV   36             // K=64 intervals
#define NSUP  18             // K=128 super-intervals (2 per barrier)
#define PXB   64             // pixels per k_main block
#define NBLK  (NPIX/PXB)     // 400 blocks
#define AST   72             // A LDS row stride in halves (144 B)
#define SUBSZ (PXB*AST)      // 4608 halves per A sub-buffer

typedef _Float16 half8 __attribute__((ext_vector_type(8)));
typedef float    f32x4 __attribute__((ext_vector_type(4)));

// -------- merged prep: x NCHW f32 -> xt NHWC f16  +  weight packs --------
#define TRN_BLOCKS 6400   // (HW/32)*(CH/32)*BATCH
__global__ __launch_bounds__(256) void k_prep(const float* __restrict__ x,
                                              _Float16* __restrict__ xt,
                                              const float* __restrict__ w,
                                              const float* __restrict__ ow,
                                              _Float16* __restrict__ wp,
                                              _Float16* __restrict__ wpo) {
    __shared__ float tile[32][33];
    int bid = blockIdx.x;
    if (bid < TRN_BLOCKS) {
        int b  = bid / 1600;
        int c0 = ((bid / 200) & 7) * 32;
        int p0 = (bid % 200) * 32;
        int tx = threadIdx.x & 31, ty = threadIdx.x >> 5;   // 32 x 8
        const float* xb = x + (size_t)b * CH * HW;
        #pragma unroll
        for (int i = 0; i < 32; i += 8)
            tile[ty + i][tx] = xb[(size_t)(c0 + ty + i) * HW + p0 + tx];
        __syncthreads();
        _Float16* xtb = xt + (size_t)b * HW * CH;
        #pragma unroll
        for (int i = 0; i < 32; i += 8)
            xtb[(size_t)(p0 + ty + i) * CH + c0 + tx] = (_Float16)tile[tx][ty + i];
        return;
    }
    int idx = (bid - TRN_BLOCKS) * 256 + threadIdx.x;
    if (idx < NIV * 16384) {
        int e    = idx & 7;
        int lane = (idx >> 3) & 63;
        int nn   = (idx >> 9) & 1;
        int ks   = (idx >> 10) & 1;
        int og   = (idx >> 11) & 7;
        int iv   = idx >> 14;
        int oc = og * 32 + nn * 16 + (lane & 15);
        int kl = ks * 32 + (lane >> 4) * 8 + e;
        int kg = iv * 64 + kl;
        int q  = kg >> 5;
        int tap = q >> 3;
        int c   = (q & 7) * 32 + (kg & 31);
        wp[idx] = (_Float16)w[((size_t)oc * CH + c) * KK + tap];
        return;
    }
    int idx2 = idx - NIV * 16384;
    if (idx2 >= NCHUNK * 1024) return;
    int e    = idx2 & 7;
    int lane = (idx2 >> 3) & 63;
    int nf   = (idx2 >> 9) & 1;
    int q    = idx2 >> 10;
    int oc  = nf * 16 + (lane & 15);
    int kic = (lane >> 4) * 8 + e;
    int tap = q >> 3;
    int c   = (q & 7) * 32 + kic;
    float v = (oc < CO) ? ow[((size_t)oc * CH + c) * KK + tap] : 0.f;
    wpo[idx2] = (_Float16)v;
}

// ---- main-loop building blocks ----
#define LOADB(DST, IV) { \
    const _Float16* wb_ = wpk4 + (size_t)(IV) * 16384 + og * 2048 + lane * 8; \
    DST[0] = *(const half8*)(wb_);        DST[1] = *(const half8*)(wb_ + 512); \
    DST[2] = *(const half8*)(wb_ + 1024); DST[3] = *(const half8*)(wb_ + 1536); }

#define LOADPRE(PRE, CWA, CHUNK) { \
    int tap_ = (CHUNK) >> 3, cg_ = (CHUNK) & 7; \
    int4 ncb_ = cbl[gpx][tap_]; float4 ncw_ = cwl[gpx][tap_]; \
    PRE[0] = *(const half8*)(xtb + (size_t)ncb_.x + cg_ * 32 + ko); \
    PRE[1] = *(const half8*)(xtb + (size_t)ncb_.y + cg_ * 32 + ko); \
    PRE[2] = *(const half8*)(xtb + (size_t)ncb_.z + cg_ * 32 + ko); \
    PRE[3] = *(const half8*)(xtb + (size_t)ncb_.w + cg_ * 32 + ko); \
    CWA[0] = ncw_.x; CWA[1] = ncw_.y; CWA[2] = ncw_.z; CWA[3] = ncw_.w; }

#define MFMA8(BASE, BF) { \
    __builtin_amdgcn_s_setprio(1); \
    _Pragma("unroll") \
    for (int mm = 0; mm < 4; ++mm) { \
      half8 a0 = *(const half8*)&(BASE)[(mm * 16 + lm) * AST + kg8]; \
      half8 a1 = *(const half8*)&(BASE)[(mm * 16 + lm) * AST + 32 + kg8]; \
      acc[mm][0] = __builtin_amdgcn_mfma_f32_16x16x32_f16(a0, BF[0], acc[mm][0], 0, 0, 0); \
      acc[mm][1] = __builtin_amdgcn_mfma_f32_16x16x32_f16(a0, BF[1], acc[mm][1], 0, 0, 0); \
      acc[mm][0] = __builtin_amdgcn_mfma_f32_16x16x32_f16(a1, BF[2], acc[mm][0], 0, 0, 0); \
      acc[mm][1] = __builtin_amdgcn_mfma_f32_16x16x32_f16(a1, BF[3], acc[mm][1], 0, 0, 0); \
    } \
    __builtin_amdgcn_s_setprio(0); }

#define BLEND(PRE, CWA, DSTBASE) { \
    half8 v_ = PRE[0] * (_Float16)CWA[0]; \
    v_ += PRE[1] * (_Float16)CWA[1]; \
    v_ += PRE[2] * (_Float16)CWA[2]; \
    v_ += PRE[3] * (_Float16)CWA[3]; \
    *(half8*)&(DSTBASE)[gpx * AST + cq * 8] = v_; }

// ---------------- fully-fused: offset-conv + corners + gather/GEMM + epilogue ----------------
// 512 thr = 8 waves. Phase 1: R16-proven (2 px-frag streams x 18-chunk K-quarter per wave).
// Main loop: 18 super-intervals (K=128), ONE barrier each; 4 A sub-buffers;
// BOTH gather prefetch sets issue right after the barrier (covered by 32 MFMAs),
// blends + next-B load at the end of the body (R18 change).
__global__ __launch_bounds__(512, 4) void k_main(const float* __restrict__ x,
                                                 const _Float16* __restrict__ xt,
                                                 const _Float16* __restrict__ wpk4,
                                                 const _Float16* __restrict__ wopf,
                                                 const float* __restrict__ obias,
                                                 const float* __restrict__ gamma,
                                                 const float* __restrict__ beta,
                                                 const float* __restrict__ mean,
                                                 const float* __restrict__ var,
                                                 float* __restrict__ out) {
    __shared__ __align__(16) char pool[55296];
    _Float16* AbF = (_Float16*)pool;                             // [4][SUBSZ] f16 = 36864 B
    int4   (*cbl)[KK] = (int4 (*)[KK])(pool + 36864);            // [64][9] = 9216 B
    float4 (*cwl)[KK] = (float4 (*)[KK])(pool + 46080);          // [64][9] = 9216 B
    float*  offl      = (float*)pool;                            // [4][64][18] f32 = 18432 B, aliases AbF

    int t = threadIdx.x, lane = t & 63, og = t >> 6;
    int lm = lane & 15, kg8 = (lane >> 4) * 8;
    // bijective XCD swizzle (400 % 8 == 0)
    int tile = ((int)blockIdx.x & 7) * (NBLK / 8) + ((int)blockIdx.x >> 3);
    int pixbase = tile * PXB;
    int bb = pixbase / HW, hw0 = pixbase % HW;
    const _Float16* xtb = xt + (size_t)bb * HW * CH;

    // ---- phase 1: offset conv via MFMA (R16-proven: 2 px-frag streams x K-quarter) ----
    {
        int pxh = og & 1;                 // pixel half: px [pxh*32, pxh*32+32)
        int kq  = og >> 1;                // K quarter: chunks [kq*18, kq*18+18)
        int apx0 = hw0 + pxh * 32 + lm;
        int apx1 = apx0 + 16;
        int h0 = apx0 / WW, w0 = apx0 % WW;
        int h1 = apx1 / WW, w1 = apx1 % WW;
        f32x4 oa0 = (f32x4)0.f, oa1 = (f32x4)0.f;
        f32x4 ob0 = (f32x4)0.f, ob1 = (f32x4)0.f;
        #pragma unroll
        for (int qq = 0; qq < 18; ++qq) {
            int q = kq * 18 + qq;
            int tap = q >> 3, cg = q & 7;
            int ki = tap / 3, kj = tap - ki * 3;
            int yy0 = h0 + ki - 1, xx0 = w0 + kj - 1;
            int yy1 = h1 + ki - 1, xx1 = w1 + kj - 1;
            bool ok0 = (yy0 >= 0) && (yy0 < HH) && (xx0 >= 0) && (xx0 < WW);
            bool ok1 = (yy1 >= 0) && (yy1 < HH) && (xx1 >= 0) && (xx1 < WW);
            half8 a0 = {0, 0, 0, 0, 0, 0, 0, 0};
            half8 a1 = {0, 0, 0, 0, 0, 0, 0, 0};
            if (ok0) a0 = *(const half8*)(xtb + (size_t)(yy0 * WW + xx0) * CH + cg * 32 + kg8);
            if (ok1) a1 = *(const half8*)(xtb + (size_t)(yy1 * WW + xx1) * CH + cg * 32 + kg8);
            const _Float16* wq = wopf + (size_t)q * 1024 + lane * 8;
            half8 b0 = *(const half8*)(wq);
            half8 b1 = *(const half8*)(wq + 512);
            oa0 = __builtin_amdgcn_mfma_f32_16x16x32_f16(a0, b0, oa0, 0, 0, 0);
            oa1 = __builtin_amdgcn_mfma_f32_16x16x32_f16(a0, b1, oa1, 0, 0, 0);
            ob0 = __builtin_amdgcn_mfma_f32_16x16x32_f16(a1, b0, ob0, 0, 0, 0);
            ob1 = __builtin_amdgcn_mfma_f32_16x16x32_f16(a1, b1, ob1, 0, 0, 0);
        }
        int prow = (lane >> 4) * 4;
        int r0 = (kq * PXB) + pxh * 32 + prow;
        int r1 = r0 + 16;
        #pragma unroll
        for (int r = 0; r < 4; ++r) {
            offl[(r0 + r) * CO + lm] = oa0[r];
            offl[(r1 + r) * CO + lm] = ob0[r];
        }
        if (lm < CO - 16) {
            #pragma unroll
            for (int r = 0; r < 4; ++r) {
                offl[(r0 + r) * CO + 16 + lm] = oa1[r];
                offl[(r1 + r) * CO + 16 + lm] = ob1[r];
            }
        }
    }
    __syncthreads();

    // ---- phase 2: bilinear corners/weights for 64 px x 9 taps -> LDS ----
    for (int task = t; task < PXB * KK; task += 512) {
        int p = task / KK, tap = task - (task / KK) * KK;
        float dy = obias[2 * tap], dx = obias[2 * tap + 1];
        #pragma unroll
        for (int ks = 0; ks < 4; ++ks) {
            dy += offl[((ks * PXB) + p) * CO + 2 * tap];
            dx += offl[((ks * PXB) + p) * CO + 2 * tap + 1];
        }
        int hw = hw0 + p, hc = hw / WW, wc = hw % WW;
        int ki = tap / 3, kj = tap - ki * 3;
        float py = dy + (float)(hc - 1 + ki);
        float px = dx + (float)(wc - 1 + kj);
        float y0f = floorf(py), x0f = floorf(px);
        float wy = py - y0f, wx = px - x0f;
        int y0 = (int)y0f, x0 = (int)x0f;
        int cb[4]; float cw[4];
        #pragma unroll
        for (int cy = 0; cy < 2; ++cy)
            #pragma unroll
            for (int cx = 0; cx < 2; ++cx) {
                int yy = y0 + cy, xx = x0 + cx;
                bool okc = (yy >= 0) && (yy < HH) && (xx >= 0) && (xx < WW);
                int yc = min(max(yy, 0), HH - 1);
                int xc = min(max(xx, 0), WW - 1);
                float wgt = (cy ? wy : 1.f - wy) * (cx ? wx : 1.f - wx);
                cb[cy * 2 + cx] = (yc * WW + xc) * CH;
                cw[cy * 2 + cx] = okc ? wgt : 0.f;
            }
        cbl[p][tap] = make_int4(cb[0], cb[1], cb[2], cb[3]);
        cwl[p][tap] = make_float4(cw[0], cw[1], cw[2], cw[3]);
    }
    __syncthreads();   // offl dead beyond this point; AbF free to overwrite

    int gpx = t >> 3, cq = t & 7;
    int sub = cq >> 2, ko = (cq & 3) * 8;

    // prologue: bfA <- B(0); gather intervals 0,1 -> buf(0,0), buf(0,1)
    half8 bfA[4], bfB[4];
    LOADB(bfA, 0)
    {
        int4 cb = cbl[gpx][0];
        float4 cw = cwl[gpx][0];
        int cg = sub;                       // interval 0: chunks 0,1 (tap 0)
        half8 v = *(const half8*)(xtb + (size_t)cb.x + cg * 32 + ko) * (_Float16)cw.x;
        v += *(const half8*)(xtb + (size_t)cb.y + cg * 32 + ko) * (_Float16)cw.y;
        v += *(const half8*)(xtb + (size_t)cb.z + cg * 32 + ko) * (_Float16)cw.z;
        v += *(const half8*)(xtb + (size_t)cb.w + cg * 32 + ko) * (_Float16)cw.w;
        *(half8*)&AbF[gpx * AST + cq * 8] = v;
        int cg2 = 2 + sub;                  // interval 1: chunks 2,3 (tap 0)
        half8 v2 = *(const half8*)(xtb + (size_t)cb.x + cg2 * 32 + ko) * (_Float16)cw.x;
        v2 += *(const half8*)(xtb + (size_t)cb.y + cg2 * 32 + ko) * (_Float16)cw.y;
        v2 += *(const half8*)(xtb + (size_t)cb.z + cg2 * 32 + ko) * (_Float16)cw.z;
        v2 += *(const half8*)(xtb + (size_t)cb.w + cg2 * 32 + ko) * (_Float16)cw.w;
        *(half8*)&AbF[SUBSZ + gpx * AST + cq * 8] = v2;
    }

    f32x4 acc[4][2];
    #pragma unroll
    for (int mm = 0; mm < 4; ++mm) {
        acc[mm][0] = (f32x4)0.f;
        acc[mm][1] = (f32x4)0.f;
    }

    // ---- main loop: 18 super-intervals, ONE barrier each ----
    // R18 body order: pres issue first (covered by 32 MFMAs), blends + next-B last.
    for (int j = 0; j < NSUP; ++j) {
        int rs = j & 1, ws = rs ^ 1;
        _Float16* bufR0 = AbF + (rs * 2 + 0) * SUBSZ;
        _Float16* bufR1 = AbF + (rs * 2 + 1) * SUBSZ;
        _Float16* bufW0 = AbF + (ws * 2 + 0) * SUBSZ;
        _Float16* bufW1 = AbF + (ws * 2 + 1) * SUBSZ;
        bool gnext = (j < NSUP - 1);
        __syncthreads();
        LOADB(bfB, 2 * j + 1)
        half8 pre0[4]; float cw0[4];
        half8 pre1[4]; float cw1[4];
        if (gnext) {
            LOADPRE(pre0, cw0, 4 * j + 4 + sub)
            LOADPRE(pre1, cw1, 4 * j + 6 + sub)
        }
        MFMA8(bufR0, bfA)                     // interval 2j
        MFMA8(bufR1, bfB)                     // interval 2j+1
        if (gnext) {
            BLEND(pre0, cw0, bufW0)
            BLEND(pre1, cw1, bufW1)
            LOADB(bfA, 2 * j + 2)
        }
    }

    // --- epilogue: BN + SiLU + residual ---
    const float* xb2  = x   + (size_t)bb * CH * HW;
    float*       outb = out + (size_t)bb * CH * HW;
    #pragma unroll
    for (int nn = 0; nn < 2; ++nn) {
        int oc = og * 32 + nn * 16 + lm;
        float sc = gamma[oc] * rsqrtf(var[oc] + 1e-5f);
        float mn = mean[oc], bt = beta[oc];
        const float* xr   = xb2  + (size_t)oc * HW + hw0;
        float*       orow = outb + (size_t)oc * HW + hw0;
        #pragma unroll
        for (int mm = 0; mm < 4; ++mm) {
            int pb2 = mm * 16 + (lane >> 4) * 4;
            #pragma unroll
            for (int r = 0; r < 4; ++r) {
                float yv = (acc[mm][nn][r] - mn) * sc + bt;
                float s = yv * __builtin_amdgcn_rcpf(1.f + __expf(-yv));
                orow[pb2 + r] = xr[pb2 + r] + s;
            }
        }
    }
}

extern "C" void kernel_launch(void* const* d_in, const int* in_sizes, int n_in,
                              void* d_out, int out_size, void* d_ws, size_t ws_size,
                              hipStream_t stream) {
    const float* x        = (const float*)d_in[0];
    const float* offset_w = (const float*)d_in[1];
    const float* offset_b = (const float*)d_in[2];
    const float* dcn_w    = (const float*)d_in[3];
    const float* gamma    = (const float*)d_in[4];
    const float* beta     = (const float*)d_in[5];
    const float* mean     = (const float*)d_in[6];
    const float* var      = (const float*)d_in[7];
    float* out = (float*)d_out;

    _Float16* xt   = (_Float16*)d_ws;                    // 13,107,200 B
    _Float16* wpk4 = xt + (size_t)NPIX * CH;             //  1,179,648 B
    _Float16* wopf = wpk4 + (size_t)NIV * 16384;         //    147,456 B

    int prep_blocks = TRN_BLOCKS + (NIV * 16384 + NCHUNK * 1024 + 255) / 256;
    k_prep<<<prep_blocks, 256, 0, stream>>>(x, xt, dcn_w, offset_w, wpk4, wopf);
    k_main<<<NBLK, 512, 0, stream>>>(x, xt, wpk4, wopf, offset_b,
                                     gamma, beta, mean, var, out);
}